// Round 6
// baseline (534.557 us; speedup 1.0000x reference)
//
#include <hip/hip_runtime.h>

typedef unsigned short u16;
typedef __attribute__((ext_vector_type(8))) short short8;
typedef __attribute__((ext_vector_type(4))) float floatx4;

#define MFMA16(A, B, C) __builtin_amdgcn_mfma_f32_16x16x32_bf16((A), (B), (C), 0, 0, 0)

// ws layout (u16 element offsets)
#define OF_SPEC  64
#define OF_SMALL (OF_SPEC + 204800)        // 8x256: W1,b1,b2,bq,bk,bv,bo,bp
#define OF_W     (OF_SMALL + 2048)         // 4x65536 swizzled: W2,Wq,Wk,Wv
#define OF_WOC   (OF_W + 4 * 65536)        // canonical Wo row-major 65536
#define OF_WPS   (OF_WOC + 65536)          // swizzled Wp 524288
#define OF_WF    (OF_WPS + 524288)         // swizzled Wfused 524288
#define OF_BF    (OF_WF + 524288)          // f32 bfused[256] (512 u16)
// total 1,583,680 u16 = 3.02 MiB

static __device__ __forceinline__ float bf2f(u16 u) {
  union { unsigned int i; float f; } z; z.i = ((unsigned int)u) << 16; return z.f;
}
static __device__ __forceinline__ u16 f2bf(float f) {
  union { float f; unsigned int i; } z; z.f = f;
  unsigned int x = z.i + 0x7fffu + ((z.i >> 16) & 1u);  // RNE
  return (u16)(x >> 16);
}
static __device__ __forceinline__ void ld8f(const u16* p, float* o) {
  union { short8 v; u16 u[8]; } t;
  t.v = *(const short8*)p;
#pragma unroll
  for (int j = 0; j < 8; ++j) o[j] = bf2f(t.u[j]);
}

__global__ void detect_kernel(const u16* __restrict__ spec_u16, int* __restrict__ flag) {
  const int lane = threadIdx.x;
  int bad = 0;
#pragma unroll
  for (int j = 0; j < 4; ++j) {
    u16 v = spec_u16[lane * 4 + j];
    int e = (v >> 7) & 0xFF;
    bad += (e >= 137);
  }
  unsigned long long m = __ballot(bad > 0);
  if (lane == 0) *flag = (__popcll(m) >= 4) ? 1 : 0;
}

#define CV(src, idx) (flag ? f2bf(((const float*)(src))[idx]) : ((const u16*)(src))[idx])

__global__ void prep_kernel(
    const int* __restrict__ flagp,
    const void* spec, const void* W1, const void* b1, const void* W2, const void* b2,
    const void* Wq, const void* bq, const void* Wk, const void* bk, const void* Wv,
    const void* bv, const void* Wo, const void* bo, const void* Wp, const void* bp,
    u16* __restrict__ ws) {
  const int flag = *flagp;
  int i = blockIdx.x * 256 + threadIdx.x;  // grid covers 1,058,816 exactly
  if (i < 204800) { ws[OF_SPEC + i] = CV(spec, i); return; }
  int j = i - 204800;
  if (j < 2048) {
    const void* srcs[8] = {W1, b1, b2, bq, bk, bv, bo, bp};
    ws[OF_SMALL + j] = CV(srcs[j >> 8], j & 255);
    return;
  }
  j -= 2048;
  if (j < 262144) {  // swizzle W2,Wq,Wk,Wv
    const void* srcs[4] = {W2, Wq, Wk, Wv};
    const int a = j >> 16, idx = j & 65535;
    const int k = idx >> 8, n = idx & 255;
    ws[OF_W + a * 65536 + (k >> 3) * 2048 + n * 8 + (k & 7)] = CV(srcs[a], idx);
    return;
  }
  j -= 262144;
  if (j < 65536) { ws[OF_WOC + j] = CV(Wo, j); return; }  // canonical Wo
  j -= 65536;
  {
    const int k = j >> 8, n = j & 255;
    ws[OF_WPS + (k >> 3) * 2048 + n * 8 + (k & 7)] = CV(Wp, j);
  }
}

// Wfused[t*256+c][n] = sum_d Wo[c][d] * Wp[t*256+d][n], stored frag-major.
// 32 blocks: b -> (t = b>>2, row-tile rt = (b&3)*64). Wave w -> cols w*64..+64.
__global__ void fusew_kernel(const u16* __restrict__ cWo, const u16* __restrict__ sWps,
                             u16* __restrict__ sWf) {
  const int t = blockIdx.x >> 2, rt = (blockIdx.x & 3) * 64;
  const int tid = threadIdx.x;
  const int w = tid >> 6, lane = tid & 63;
  const int l15 = lane & 15, quad = lane >> 4;
  floatx4 acc[4][4];
#pragma unroll
  for (int mi = 0; mi < 4; ++mi)
#pragma unroll
    for (int ni = 0; ni < 4; ++ni) acc[mi][ni] = (floatx4){0.f, 0.f, 0.f, 0.f};
#pragma unroll
  for (int kc = 0; kc < 8; ++kc) {
    short8 afr[4];
#pragma unroll
    for (int mi = 0; mi < 4; ++mi)
      afr[mi] = *(const short8*)(cWo + (rt + mi * 16 + l15) * 256 + kc * 32 + quad * 8);
#pragma unroll
    for (int ni = 0; ni < 4; ++ni) {
      const int n = w * 64 + ni * 16 + l15;
      short8 bfr = *(const short8*)(sWps + (t * 32 + kc * 4 + quad) * 2048 + n * 8);
#pragma unroll
      for (int mi = 0; mi < 4; ++mi) acc[mi][ni] = MFMA16(afr[mi], bfr, acc[mi][ni]);
    }
  }
#pragma unroll
  for (int mi = 0; mi < 4; ++mi)
#pragma unroll
    for (int ni = 0; ni < 4; ++ni) {
      const int n = w * 64 + ni * 16 + l15;
#pragma unroll
      for (int r = 0; r < 4; ++r) {
        const int c = rt + mi * 16 + quad * 4 + r;
        sWf[(t * 32 + (c >> 3)) * 2048 + n * 8 + (c & 7)] = f2bf(acc[mi][ni][r]);
      }
    }
}

// bfused[n] = bp[n] + sum_{t,d} bo[d] * Wp[t*256+d][n]
__global__ void bfused_kernel(const u16* __restrict__ csm, const u16* __restrict__ sWps,
                              float* __restrict__ fbf) {
  const int n = threadIdx.x;
  float acc = bf2f(csm[1792 + n]);  // bp
#pragma unroll 8
  for (int k = 0; k < 2048; ++k)
    acc = fmaf(bf2f(csm[1536 + (k & 255)]),
               bf2f(sWps[(k >> 3) * 2048 + n * 8 + (k & 7)]), acc);
  fbf[n] = acc;
}

// One block = 64 tokens = 8 windows. TWO barriers total:
//   phase0 e -> eA (barrier) -> per-wave own 16 rows: 8x[QKV 32 cols -> attention
//   -> O into Ofull] all program-ordered DS (no barriers) -> (barrier) ->
//   patch GEMM [8 x 2048] @ Wfused + bfused.
__global__ __launch_bounds__(256, 2) void fused_kernel(
    const u16* __restrict__ csp, const u16* __restrict__ csm,
    const u16* __restrict__ sW2, const u16* __restrict__ sWq,
    const u16* __restrict__ sWk, const u16* __restrict__ sWv,
    const u16* __restrict__ sWf, const float* __restrict__ fbf,
    const int* __restrict__ flagp,
    void* __restrict__ out)
{
  __shared__ u16 lds[38912];          // 77824 B -> 2 blocks/CU
  u16* eA = lds;                      // 16384: frag-major e A[m64][k256]
  u16* Of = lds + 16384;              // 16384: patch A frag-major [k2048][win8]
  u16* st = lds + 32768;              // 6144: per-wave staging [w][q512|k512|v512]

  const u16* cW1 = csm;
  const u16* cb1 = csm + 256;
  const u16* cb2 = csm + 512;
  const u16* cbq = csm + 768;
  const u16* cbk = csm + 1024;
  const u16* cbv = csm + 1280;

  const int flag = *flagp;
  const int tid = threadIdx.x;
  const int w = tid >> 6, lane = tid & 63;
  const int l15 = lane & 15, quad = lane >> 4;
  const int tile0 = blockIdx.x * 64;

  float sv[4];
#pragma unroll
  for (int mi = 0; mi < 4; ++mi) sv[mi] = bf2f(csp[tile0 + mi * 16 + l15]);

  // ---------------- phase 0: e tile -> eA fragment-major ----------------
  {
    const int nbase = w * 64;
    floatx4 acc[4][4];
#pragma unroll
    for (int mi = 0; mi < 4; ++mi)
#pragma unroll
      for (int ni = 0; ni < 4; ++ni) acc[mi][ni] = (floatx4){0.f, 0.f, 0.f, 0.f};
    for (int kc = 0; kc < 8; ++kc) {
      const int k0 = kc * 32 + quad * 8;
      float w1f[8], b1f[8];
      ld8f(cW1 + k0, w1f);
      ld8f(cb1 + k0, b1f);
      short8 afr[4];
#pragma unroll
      for (int mi = 0; mi < 4; ++mi) {
        union { short8 s; u16 u[8]; } av;
#pragma unroll
        for (int j = 0; j < 8; ++j) {
          float x = fmaf(sv[mi], w1f[j], b1f[j]);
          av.u[j] = f2bf(x > 0.f ? x : 0.f);
        }
        afr[mi] = av.s;
      }
#pragma unroll
      for (int ni = 0; ni < 4; ++ni) {
        short8 bfr = *(const short8*)(sW2 + ((kc * 4 + quad) * 256 + nbase + ni * 16 + l15) * 8);
#pragma unroll
        for (int mi = 0; mi < 4; ++mi) acc[mi][ni] = MFMA16(afr[mi], bfr, acc[mi][ni]);
      }
    }
#pragma unroll
    for (int ni = 0; ni < 4; ++ni) {
      const int n = nbase + ni * 16 + l15;
      const float bb = bf2f(cb2[n]);
      const int blk = (n >> 3) * 512 + (n & 7);
#pragma unroll
      for (int mi = 0; mi < 4; ++mi)
#pragma unroll
        for (int r = 0; r < 4; ++r)
          eA[blk + (mi * 16 + quad * 4 + r) * 8] = f2bf(acc[mi][ni][r] + bb);
    }
  }
  __syncthreads();   // BARRIER 1: eA complete

  // ---------------- 8 heads, all own-wave (no barriers) -----------------
  u16* sq = st + w * 1536;   // Q stage / P overlay (A-frag layout)
  u16* sk = sq + 512;        // K stage (B-frag layout)
  u16* sv8 = sq + 1024;      // V stage (B-frag layout, 2 dh halves)
  const int wwin = w * 2 + (quad >> 1);
  const int tq = (quad & 1) * 4;     // token-in-window base for this quad

  for (int h = 0; h < 8; ++h) {
    // QKV: own 16 rows (w*16..+16) x 32 cols (h*32..+32)
    floatx4 facc[3][2];
#pragma unroll
    for (int x = 0; x < 3; ++x)
#pragma unroll
      for (int ni = 0; ni < 2; ++ni) facc[x][ni] = (floatx4){0.f, 0.f, 0.f, 0.f};
#pragma unroll
    for (int kc = 0; kc < 8; ++kc) {
      short8 afr = *(const short8*)(eA + (kc * 4 + quad) * 512 + (w * 16 + l15) * 8);
#pragma unroll
      for (int ni = 0; ni < 2; ++ni) {
        const int wo = ((kc * 4 + quad) * 256 + h * 32 + ni * 16 + l15) * 8;
        facc[0][ni] = MFMA16(afr, *(const short8*)(sWq + wo), facc[0][ni]);
        facc[1][ni] = MFMA16(afr, *(const short8*)(sWk + wo), facc[1][ni]);
        facc[2][ni] = MFMA16(afr, *(const short8*)(sWv + wo), facc[2][ni]);
      }
    }
    // stage q,k,v (own region; C-layout -> frag layouts)
#pragma unroll
    for (int ni = 0; ni < 2; ++ni) {
      const int n = h * 32 + ni * 16 + l15;
      const float bq_ = bf2f(cbq[n]), bk_ = bf2f(cbk[n]), bv_ = bf2f(cbv[n]);
      const int dblk = ni * 2 + (l15 >> 3), d7 = l15 & 7;
#pragma unroll
      for (int r = 0; r < 4; ++r) {
        const int m15 = quad * 4 + r;
        sq[dblk * 128 + m15 * 8 + d7] = f2bf(facc[0][ni][r] + bq_);
        sk[dblk * 128 + m15 * 8 + d7] = f2bf(facc[1][ni][r] + bk_);
        sv8[ni * 256 + (m15 >> 3) * 128 + l15 * 8 + (m15 & 7)] = f2bf(facc[2][ni][r] + bv_);
      }
    }
    // attention (own wave, program-ordered DS)
    {
      short8 aq = *(const short8*)(sq + quad * 128 + l15 * 8);
      short8 bk8 = *(const short8*)(sk + quad * 128 + l15 * 8);
      floatx4 sacc = MFMA16(aq, bk8, ((floatx4){0.f, 0.f, 0.f, 0.f}));
      const int valid = ((l15 >> 3) == (quad >> 1));
      u16 pb[4];
#pragma unroll
      for (int r = 0; r < 4; ++r) {
        float s = valid ? sacc[r] * 0.17677669529663687f : -1e30f;
        float mx = s;
        mx = fmaxf(mx, __shfl_xor(mx, 1));
        mx = fmaxf(mx, __shfl_xor(mx, 2));
        mx = fmaxf(mx, __shfl_xor(mx, 4));
        mx = fmaxf(mx, __shfl_xor(mx, 8));
        float p = __expf(s - mx);
        float su = p;
        su += __shfl_xor(su, 1);
        su += __shfl_xor(su, 2);
        su += __shfl_xor(su, 4);
        su += __shfl_xor(su, 8);
        pb[r] = f2bf(p * (1.0f / su));
      }
      // P -> A-frag overlay of sq
      *(unsigned long long*)(sq + 256 + lane * 4) = 0ULL;
#pragma unroll
      for (int r = 0; r < 4; ++r)
        sq[(l15 >> 3) * 128 + (quad * 4 + r) * 8 + (l15 & 7)] = pb[r];

      short8 ap = *(const short8*)(sq + quad * 128 + l15 * 8);
#pragma unroll
      for (int dh = 0; dh < 2; ++dh) {
        short8 bv8 = *(const short8*)(sv8 + dh * 256 + (quad & 1) * 128 + l15 * 8);
        floatx4 oacc = MFMA16(ap, bv8, ((floatx4){0.f, 0.f, 0.f, 0.f}));
        // O -> Ofull in patch-A frag layout: k = t*256 + h*32 + dh*16 + l15
#pragma unroll
        for (int r = 0; r < 4; ++r) {
          const int t = tq + r;
          Of[(t * 32 + h * 4 + dh * 2 + (l15 >> 3)) * 64 + wwin * 8 + (l15 & 7)] =
              f2bf(oacc[r]);
        }
      }
    }
  }
  __syncthreads();   // BARRIER 2: Ofull complete

  // ---------------- patch projection: [8 x 2048] @ Wfused + bfused --------
  {
    const int w8 = (l15 & 7) * 8;
    floatx4 pacc[4];
#pragma unroll
    for (int ni = 0; ni < 4; ++ni) pacc[ni] = (floatx4){0.f, 0.f, 0.f, 0.f};
#pragma unroll 4
    for (int kc = 0; kc < 64; ++kc) {
      short8 afr = *(const short8*)(Of + (kc * 4 + quad) * 64 + w8);
#pragma unroll
      for (int ni = 0; ni < 4; ++ni) {
        const int n = w * 64 + ni * 16 + l15;
        short8 bfr = *(const short8*)(sWf + ((kc * 4 + quad) * 256 + n) * 8);
        pacc[ni] = MFMA16(afr, bfr, pacc[ni]);
      }
    }
    if (quad < 2) {
      if (flag) {
        float* po = (float*)out;
#pragma unroll
        for (int ni = 0; ni < 4; ++ni) {
          const int n = w * 64 + ni * 16 + l15;
          const float bb = fbf[n];
#pragma unroll
          for (int r = 0; r < 4; ++r)
            po[(blockIdx.x * 8 + quad * 4 + r) * 256 + n] = pacc[ni][r] + bb;
        }
      } else {
        u16* po = (u16*)out;
#pragma unroll
        for (int ni = 0; ni < 4; ++ni) {
          const int n = w * 64 + ni * 16 + l15;
          const float bb = fbf[n];
#pragma unroll
          for (int r = 0; r < 4; ++r)
            po[(blockIdx.x * 8 + quad * 4 + r) * 256 + n] = f2bf(pacc[ni][r] + bb);
        }
      }
    }
  }
}

extern "C" void kernel_launch(void* const* d_in, const int* in_sizes, int n_in,
                              void* d_out, int out_size, void* d_ws, size_t ws_size,
                              hipStream_t stream) {
  (void)in_sizes; (void)n_in; (void)out_size; (void)ws_size;
  int* flag = (int*)d_ws;
  u16* ws = (u16*)d_ws;

  detect_kernel<<<1, 64, 0, stream>>>((const u16*)d_in[0], flag);
  prep_kernel<<<4136, 256, 0, stream>>>(flag,
      d_in[0], d_in[1], d_in[2], d_in[3], d_in[4], d_in[5], d_in[6], d_in[7],
      d_in[8], d_in[9], d_in[10], d_in[11], d_in[12], d_in[13], d_in[14], ws);
  fusew_kernel<<<32, 256, 0, stream>>>(ws + OF_WOC, ws + OF_WPS, ws + OF_WF);
  bfused_kernel<<<1, 256, 0, stream>>>(ws + OF_SMALL, ws + OF_WPS,
                                       (float*)(ws + OF_BF));
  fused_kernel<<<3200, 256, 0, stream>>>(
      ws + OF_SPEC, ws + OF_SMALL,
      ws + OF_W, ws + OF_W + 65536, ws + OF_W + 2 * 65536, ws + OF_W + 3 * 65536,
      ws + OF_WF, (const float*)(ws + OF_BF),
      flag, d_out);
}

// Round 7
// 495.090 us; speedup vs baseline: 1.0797x; 1.0797x over previous
//
#include <hip/hip_runtime.h>

typedef unsigned short u16;
typedef __attribute__((ext_vector_type(8))) short short8;
typedef __attribute__((ext_vector_type(4))) float floatx4;

#define MFMA16(A, B, C) __builtin_amdgcn_mfma_f32_16x16x32_bf16((A), (B), (C), 0, 0, 0)

// ws layout (u16 element offsets)
#define OF_SPEC  64
#define OF_SMALL (OF_SPEC + 204800)        // 8x256: W1,b1,b2,bq,bk,bv,bo,bp
#define OF_W     (OF_SMALL + 2048)         // 4x65536 swizzled: W2,Wq,Wk,Wv
#define OF_WOC   (OF_W + 4 * 65536)        // canonical Wo row-major 65536
#define OF_WPS   (OF_WOC + 65536)          // swizzled Wp 524288
#define OF_WF    (OF_WPS + 524288)         // swizzled Wfused 524288
#define OF_BF    (OF_WF + 524288)          // f32 bfused[256] (512 u16)
#define OF_AG    (OF_BF + 512)             // O in patch-A frag order [256 kblk][25600 win][8]
#define AG_ELEMS 52428800ull
#define WS_NEED  ((unsigned long long)(OF_AG + AG_ELEMS) * 2ull)

static __device__ __forceinline__ float bf2f(u16 u) {
  union { unsigned int i; float f; } z; z.i = ((unsigned int)u) << 16; return z.f;
}
static __device__ __forceinline__ u16 f2bf(float f) {
  union { float f; unsigned int i; } z; z.f = f;
  unsigned int x = z.i + 0x7fffu + ((z.i >> 16) & 1u);  // RNE
  return (u16)(x >> 16);
}
static __device__ __forceinline__ void ld8f(const u16* p, float* o) {
  union { short8 v; u16 u[8]; } t;
  t.v = *(const short8*)p;
#pragma unroll
  for (int j = 0; j < 8; ++j) o[j] = bf2f(t.u[j]);
}

__global__ void detect_kernel(const u16* __restrict__ spec_u16, int* __restrict__ flag) {
  const int lane = threadIdx.x;
  int bad = 0;
#pragma unroll
  for (int j = 0; j < 4; ++j) {
    u16 v = spec_u16[lane * 4 + j];
    int e = (v >> 7) & 0xFF;
    bad += (e >= 137);
  }
  unsigned long long m = __ballot(bad > 0);
  if (lane == 0) *flag = (__popcll(m) >= 4) ? 1 : 0;
}

#define CV(src, idx) (flag ? f2bf(((const float*)(src))[idx]) : ((const u16*)(src))[idx])

__global__ void prep_kernel(
    const int* __restrict__ flagp,
    const void* spec, const void* W1, const void* b1, const void* W2, const void* b2,
    const void* Wq, const void* bq, const void* Wk, const void* bk, const void* Wv,
    const void* bv, const void* Wo, const void* bo, const void* Wp, const void* bp,
    u16* __restrict__ ws) {
  const int flag = *flagp;
  int i = blockIdx.x * 256 + threadIdx.x;  // grid covers 1,058,816 exactly
  if (i < 204800) { ws[OF_SPEC + i] = CV(spec, i); return; }
  int j = i - 204800;
  if (j < 2048) {
    const void* srcs[8] = {W1, b1, b2, bq, bk, bv, bo, bp};
    ws[OF_SMALL + j] = CV(srcs[j >> 8], j & 255);
    return;
  }
  j -= 2048;
  if (j < 262144) {  // swizzle W2,Wq,Wk,Wv
    const void* srcs[4] = {W2, Wq, Wk, Wv};
    const int a = j >> 16, idx = j & 65535;
    const int k = idx >> 8, n = idx & 255;
    ws[OF_W + a * 65536 + (k >> 3) * 2048 + n * 8 + (k & 7)] = CV(srcs[a], idx);
    return;
  }
  j -= 262144;
  if (j < 65536) { ws[OF_WOC + j] = CV(Wo, j); return; }  // canonical Wo
  j -= 65536;
  {
    const int k = j >> 8, n = j & 255;
    ws[OF_WPS + (k >> 3) * 2048 + n * 8 + (k & 7)] = CV(Wp, j);
  }
}

// Wfused[t*256+c][n] = sum_d Wo[c][d] * Wp[t*256+d][n], stored frag-major.
__global__ void fusew_kernel(const u16* __restrict__ cWo, const u16* __restrict__ sWps,
                             u16* __restrict__ sWf) {
  const int t = blockIdx.x >> 2, rt = (blockIdx.x & 3) * 64;
  const int tid = threadIdx.x;
  const int w = tid >> 6, lane = tid & 63;
  const int l15 = lane & 15, quad = lane >> 4;
  floatx4 acc[4][4];
#pragma unroll
  for (int mi = 0; mi < 4; ++mi)
#pragma unroll
    for (int ni = 0; ni < 4; ++ni) acc[mi][ni] = (floatx4){0.f, 0.f, 0.f, 0.f};
#pragma unroll
  for (int kc = 0; kc < 8; ++kc) {
    short8 afr[4];
#pragma unroll
    for (int mi = 0; mi < 4; ++mi)
      afr[mi] = *(const short8*)(cWo + (rt + mi * 16 + l15) * 256 + kc * 32 + quad * 8);
#pragma unroll
    for (int ni = 0; ni < 4; ++ni) {
      const int n = w * 64 + ni * 16 + l15;
      short8 bfr = *(const short8*)(sWps + (t * 32 + kc * 4 + quad) * 2048 + n * 8);
#pragma unroll
      for (int mi = 0; mi < 4; ++mi) acc[mi][ni] = MFMA16(afr[mi], bfr, acc[mi][ni]);
    }
  }
#pragma unroll
  for (int mi = 0; mi < 4; ++mi)
#pragma unroll
    for (int ni = 0; ni < 4; ++ni) {
      const int n = w * 64 + ni * 16 + l15;
#pragma unroll
      for (int r = 0; r < 4; ++r) {
        const int c = rt + mi * 16 + quad * 4 + r;
        sWf[(t * 32 + (c >> 3)) * 2048 + n * 8 + (c & 7)] = f2bf(acc[mi][ni][r]);
      }
    }
}

// bfused[n] = bp[n] + sum_{t,d} bo[d] * Wp[t*256+d][n]
__global__ void bfused_kernel(const u16* __restrict__ csm, const u16* __restrict__ sWps,
                              float* __restrict__ fbf) {
  const int n = threadIdx.x;
  float acc = bf2f(csm[1792 + n]);  // bp
#pragma unroll 8
  for (int k = 0; k < 2048; ++k)
    acc = fmaf(bf2f(csm[1536 + (k & 255)]),
               bf2f(sWps[(k >> 3) * 2048 + n * 8 + (k & 7)]), acc);
  fbf[n] = acc;
}

// ======================= SPLIT PATH: K1 =======================
// embed + QKV + MFMA attention; O -> global AG in patch-A frag order.
// LDS 48 KB -> 3 blocks/CU; softmax has no max pass (scores << 88).
__global__ __launch_bounds__(256, 3) void attn_kernel(
    const u16* __restrict__ csp, const u16* __restrict__ csm,
    const u16* __restrict__ sW2, const u16* __restrict__ sWq,
    const u16* __restrict__ sWk, const u16* __restrict__ sWv,
    u16* __restrict__ AG)
{
  __shared__ u16 lds[24576];          // 49152 B
  u16* eA = lds;                      // 16384: frag-major e A[m64][k256]
  u16* st = lds + 16384;              // 4 waves x 2048: sq|sk|sv|sp (512 each)

  const u16* cW1 = csm;
  const u16* cb1 = csm + 256;
  const u16* cb2 = csm + 512;
  const u16* cbq = csm + 768;
  const u16* cbk = csm + 1024;
  const u16* cbv = csm + 1280;

  const int tid = threadIdx.x;
  const int w = tid >> 6, lane = tid & 63;
  const int l15 = lane & 15, quad = lane >> 4;
  const int tile0 = blockIdx.x * 64;

  float sv[4];
#pragma unroll
  for (int mi = 0; mi < 4; ++mi) sv[mi] = bf2f(csp[tile0 + mi * 16 + l15]);

  // ---------------- phase 0: e tile -> eA fragment-major ----------------
  {
    const int nbase = w * 64;
    floatx4 acc[4][4];
#pragma unroll
    for (int mi = 0; mi < 4; ++mi)
#pragma unroll
      for (int ni = 0; ni < 4; ++ni) acc[mi][ni] = (floatx4){0.f, 0.f, 0.f, 0.f};
    for (int kc = 0; kc < 8; ++kc) {
      const int k0 = kc * 32 + quad * 8;
      float w1f[8], b1f[8];
      ld8f(cW1 + k0, w1f);
      ld8f(cb1 + k0, b1f);
      short8 afr[4];
#pragma unroll
      for (int mi = 0; mi < 4; ++mi) {
        union { short8 s; u16 u[8]; } av;
#pragma unroll
        for (int j = 0; j < 8; ++j) {
          float x = fmaf(sv[mi], w1f[j], b1f[j]);
          av.u[j] = f2bf(x > 0.f ? x : 0.f);
        }
        afr[mi] = av.s;
      }
#pragma unroll
      for (int ni = 0; ni < 4; ++ni) {
        short8 bfr = *(const short8*)(sW2 + ((kc * 4 + quad) * 256 + nbase + ni * 16 + l15) * 8);
#pragma unroll
        for (int mi = 0; mi < 4; ++mi) acc[mi][ni] = MFMA16(afr[mi], bfr, acc[mi][ni]);
      }
    }
#pragma unroll
    for (int ni = 0; ni < 4; ++ni) {
      const int n = nbase + ni * 16 + l15;
      const float bb = bf2f(cb2[n]);
      const int blk = (n >> 3) * 512 + (n & 7);
#pragma unroll
      for (int mi = 0; mi < 4; ++mi)
#pragma unroll
        for (int r = 0; r < 4; ++r)
          eA[blk + (mi * 16 + quad * 4 + r) * 8] = f2bf(acc[mi][ni][r] + bb);
    }
  }
  __syncthreads();   // the only barrier

  // ---------------- 8 heads, all own-wave ------------------------------
  u16* sq = st + w * 2048;
  u16* sk = sq + 512;
  u16* sv8 = sq + 1024;
  u16* sp = sq + 1536;
  *(unsigned long long*)(sp + 256 + lane * 4) = 0ULL;  // P pad: zero ONCE

  const int wwin = w * 2 + (quad >> 1);
  const int tq = (quad & 1) * 4;
  const int wing = blockIdx.x * 8 + wwin;

  for (int h = 0; h < 8; ++h) {
    // QKV: own 16 rows (w*16..+16) x 32 cols (h*32..+32)
    floatx4 facc[3][2];
#pragma unroll
    for (int x = 0; x < 3; ++x)
#pragma unroll
      for (int ni = 0; ni < 2; ++ni) facc[x][ni] = (floatx4){0.f, 0.f, 0.f, 0.f};
#pragma unroll
    for (int kc = 0; kc < 8; ++kc) {
      short8 afr = *(const short8*)(eA + (kc * 4 + quad) * 512 + (w * 16 + l15) * 8);
#pragma unroll
      for (int ni = 0; ni < 2; ++ni) {
        const int wo = ((kc * 4 + quad) * 256 + h * 32 + ni * 16 + l15) * 8;
        facc[0][ni] = MFMA16(afr, *(const short8*)(sWq + wo), facc[0][ni]);
        facc[1][ni] = MFMA16(afr, *(const short8*)(sWk + wo), facc[1][ni]);
        facc[2][ni] = MFMA16(afr, *(const short8*)(sWv + wo), facc[2][ni]);
      }
    }
    // stage q,k,v (own region; C-layout -> frag layouts)
#pragma unroll
    for (int ni = 0; ni < 2; ++ni) {
      const int n = h * 32 + ni * 16 + l15;
      const float bq_ = bf2f(cbq[n]), bk_ = bf2f(cbk[n]), bv_ = bf2f(cbv[n]);
      const int dblk = ni * 2 + (l15 >> 3), d7 = l15 & 7;
#pragma unroll
      for (int r = 0; r < 4; ++r) {
        const int m15 = quad * 4 + r;
        sq[dblk * 128 + m15 * 8 + d7] = f2bf(facc[0][ni][r] + bq_);
        sk[dblk * 128 + m15 * 8 + d7] = f2bf(facc[1][ni][r] + bk_);
        sv8[ni * 256 + (m15 >> 3) * 128 + l15 * 8 + (m15 & 7)] = f2bf(facc[2][ni][r] + bv_);
      }
    }
    // attention (own wave, program-ordered DS); no-max softmax
    {
      short8 aq = *(const short8*)(sq + quad * 128 + l15 * 8);
      short8 bk8 = *(const short8*)(sk + quad * 128 + l15 * 8);
      floatx4 sacc = MFMA16(aq, bk8, ((floatx4){0.f, 0.f, 0.f, 0.f}));
      const int valid = ((l15 >> 3) == (quad >> 1));
      float invl[4];
#pragma unroll
      for (int r = 0; r < 4; ++r) {
        float s = sacc[r] * 0.17677669529663687f;  // 1/sqrt(32)
        float p = valid ? __expf(s) : 0.f;
        sp[(l15 >> 3) * 128 + (quad * 4 + r) * 8 + (l15 & 7)] = f2bf(p);
        float su = p;
        su += __shfl_xor(su, 1);
        su += __shfl_xor(su, 2);
        su += __shfl_xor(su, 4);
        su += __shfl_xor(su, 8);
        invl[r] = 1.f / su;
      }
      short8 ap = *(const short8*)(sp + quad * 128 + l15 * 8);
#pragma unroll
      for (int dh = 0; dh < 2; ++dh) {
        short8 bv8 = *(const short8*)(sv8 + dh * 256 + (quad & 1) * 128 + l15 * 8);
        floatx4 oacc = MFMA16(ap, bv8, ((floatx4){0.f, 0.f, 0.f, 0.f}));
        // O -> AG in patch-A frag order: k = t*256 + h*32 + dh*16 + l15
#pragma unroll
        for (int r = 0; r < 4; ++r) {
          const int kblk = (tq + r) * 32 + h * 4 + dh * 2 + (l15 >> 3);
          AG[kblk * 204800 + wing * 8 + (l15 & 7)] = f2bf(oacc[r] * invl[r]);
        }
      }
    }
  }
}

// ======================= SPLIT PATH: K2 =======================
// out[25600 x 256] = AG[25600 x 2048] @ Wfused + bfused. 800 blocks x 32 wins.
__global__ __launch_bounds__(256, 4) void patch_kernel(
    const u16* __restrict__ AG, const u16* __restrict__ sWf,
    const float* __restrict__ fbf, const int* __restrict__ flagp,
    void* __restrict__ out)
{
  const int tid = threadIdx.x;
  const int w = tid >> 6, lane = tid & 63;
  const int l15 = lane & 15, quad = lane >> 4;
  const int m0 = blockIdx.x * 32;
  const int flag = *flagp;

  floatx4 acc[2][4];
#pragma unroll
  for (int mi = 0; mi < 2; ++mi)
#pragma unroll
    for (int ni = 0; ni < 4; ++ni) acc[mi][ni] = (floatx4){0.f, 0.f, 0.f, 0.f};
#pragma unroll 4
  for (int kc = 0; kc < 64; ++kc) {
    short8 afr[2];
#pragma unroll
    for (int mi = 0; mi < 2; ++mi)
      afr[mi] = *(const short8*)(AG + (kc * 4 + quad) * 204800 + (m0 + mi * 16 + l15) * 8);
#pragma unroll
    for (int ni = 0; ni < 4; ++ni) {
      const int n = w * 64 + ni * 16 + l15;
      short8 bfr = *(const short8*)(sWf + ((kc * 4 + quad) * 256 + n) * 8);
#pragma unroll
      for (int mi = 0; mi < 2; ++mi) acc[mi][ni] = MFMA16(afr[mi], bfr, acc[mi][ni]);
    }
  }
  if (flag) {
    float* po = (float*)out;
#pragma unroll
    for (int mi = 0; mi < 2; ++mi)
#pragma unroll
      for (int ni = 0; ni < 4; ++ni) {
        const int n = w * 64 + ni * 16 + l15;
        const float bb = fbf[n];
#pragma unroll
        for (int r = 0; r < 4; ++r)
          po[(m0 + mi * 16 + quad * 4 + r) * 256 + n] = acc[mi][ni][r] + bb;
      }
  } else {
    u16* po = (u16*)out;
#pragma unroll
    for (int mi = 0; mi < 2; ++mi)
#pragma unroll
      for (int ni = 0; ni < 4; ++ni) {
        const int n = w * 64 + ni * 16 + l15;
        const float bb = fbf[n];
#pragma unroll
        for (int r = 0; r < 4; ++r)
          po[(m0 + mi * 16 + quad * 4 + r) * 256 + n] = f2bf(acc[mi][ni][r] + bb);
      }
  }
}

// ======================= FALLBACK: round-6 fused =======================
__global__ __launch_bounds__(256, 2) void fused_kernel(
    const u16* __restrict__ csp, const u16* __restrict__ csm,
    const u16* __restrict__ sW2, const u16* __restrict__ sWq,
    const u16* __restrict__ sWk, const u16* __restrict__ sWv,
    const u16* __restrict__ sWf, const float* __restrict__ fbf,
    const int* __restrict__ flagp,
    void* __restrict__ out)
{
  __shared__ u16 lds[38912];
  u16* eA = lds;
  u16* Of = lds + 16384;
  u16* st = lds + 32768;

  const u16* cW1 = csm;
  const u16* cb1 = csm + 256;
  const u16* cb2 = csm + 512;
  const u16* cbq = csm + 768;
  const u16* cbk = csm + 1024;
  const u16* cbv = csm + 1280;

  const int flag = *flagp;
  const int tid = threadIdx.x;
  const int w = tid >> 6, lane = tid & 63;
  const int l15 = lane & 15, quad = lane >> 4;
  const int tile0 = blockIdx.x * 64;

  float sv[4];
#pragma unroll
  for (int mi = 0; mi < 4; ++mi) sv[mi] = bf2f(csp[tile0 + mi * 16 + l15]);

  {
    const int nbase = w * 64;
    floatx4 acc[4][4];
#pragma unroll
    for (int mi = 0; mi < 4; ++mi)
#pragma unroll
      for (int ni = 0; ni < 4; ++ni) acc[mi][ni] = (floatx4){0.f, 0.f, 0.f, 0.f};
    for (int kc = 0; kc < 8; ++kc) {
      const int k0 = kc * 32 + quad * 8;
      float w1f[8], b1f[8];
      ld8f(cW1 + k0, w1f);
      ld8f(cb1 + k0, b1f);
      short8 afr[4];
#pragma unroll
      for (int mi = 0; mi < 4; ++mi) {
        union { short8 s; u16 u[8]; } av;
#pragma unroll
        for (int j = 0; j < 8; ++j) {
          float x = fmaf(sv[mi], w1f[j], b1f[j]);
          av.u[j] = f2bf(x > 0.f ? x : 0.f);
        }
        afr[mi] = av.s;
      }
#pragma unroll
      for (int ni = 0; ni < 4; ++ni) {
        short8 bfr = *(const short8*)(sW2 + ((kc * 4 + quad) * 256 + nbase + ni * 16 + l15) * 8);
#pragma unroll
        for (int mi = 0; mi < 4; ++mi) acc[mi][ni] = MFMA16(afr[mi], bfr, acc[mi][ni]);
      }
    }
#pragma unroll
    for (int ni = 0; ni < 4; ++ni) {
      const int n = nbase + ni * 16 + l15;
      const float bb = bf2f(cb2[n]);
      const int blk = (n >> 3) * 512 + (n & 7);
#pragma unroll
      for (int mi = 0; mi < 4; ++mi)
#pragma unroll
        for (int r = 0; r < 4; ++r)
          eA[blk + (mi * 16 + quad * 4 + r) * 8] = f2bf(acc[mi][ni][r] + bb);
    }
  }
  __syncthreads();

  u16* sq = st + w * 1536;
  u16* sk = sq + 512;
  u16* sv8 = sq + 1024;
  const int wwin = w * 2 + (quad >> 1);
  const int tq = (quad & 1) * 4;

  for (int h = 0; h < 8; ++h) {
    floatx4 facc[3][2];
#pragma unroll
    for (int x = 0; x < 3; ++x)
#pragma unroll
      for (int ni = 0; ni < 2; ++ni) facc[x][ni] = (floatx4){0.f, 0.f, 0.f, 0.f};
#pragma unroll
    for (int kc = 0; kc < 8; ++kc) {
      short8 afr = *(const short8*)(eA + (kc * 4 + quad) * 512 + (w * 16 + l15) * 8);
#pragma unroll
      for (int ni = 0; ni < 2; ++ni) {
        const int wo = ((kc * 4 + quad) * 256 + h * 32 + ni * 16 + l15) * 8;
        facc[0][ni] = MFMA16(afr, *(const short8*)(sWq + wo), facc[0][ni]);
        facc[1][ni] = MFMA16(afr, *(const short8*)(sWk + wo), facc[1][ni]);
        facc[2][ni] = MFMA16(afr, *(const short8*)(sWv + wo), facc[2][ni]);
      }
    }
#pragma unroll
    for (int ni = 0; ni < 2; ++ni) {
      const int n = h * 32 + ni * 16 + l15;
      const float bq_ = bf2f(cbq[n]), bk_ = bf2f(cbk[n]), bv_ = bf2f(cbv[n]);
      const int dblk = ni * 2 + (l15 >> 3), d7 = l15 & 7;
#pragma unroll
      for (int r = 0; r < 4; ++r) {
        const int m15 = quad * 4 + r;
        sq[dblk * 128 + m15 * 8 + d7] = f2bf(facc[0][ni][r] + bq_);
        sk[dblk * 128 + m15 * 8 + d7] = f2bf(facc[1][ni][r] + bk_);
        sv8[ni * 256 + (m15 >> 3) * 128 + l15 * 8 + (m15 & 7)] = f2bf(facc[2][ni][r] + bv_);
      }
    }
    {
      short8 aq = *(const short8*)(sq + quad * 128 + l15 * 8);
      short8 bk8 = *(const short8*)(sk + quad * 128 + l15 * 8);
      floatx4 sacc = MFMA16(aq, bk8, ((floatx4){0.f, 0.f, 0.f, 0.f}));
      const int valid = ((l15 >> 3) == (quad >> 1));
      u16 pb[4];
#pragma unroll
      for (int r = 0; r < 4; ++r) {
        float s = valid ? sacc[r] * 0.17677669529663687f : -1e30f;
        float mx = s;
        mx = fmaxf(mx, __shfl_xor(mx, 1));
        mx = fmaxf(mx, __shfl_xor(mx, 2));
        mx = fmaxf(mx, __shfl_xor(mx, 4));
        mx = fmaxf(mx, __shfl_xor(mx, 8));
        float p = __expf(s - mx);
        float su = p;
        su += __shfl_xor(su, 1);
        su += __shfl_xor(su, 2);
        su += __shfl_xor(su, 4);
        su += __shfl_xor(su, 8);
        pb[r] = f2bf(p * (1.0f / su));
      }
      *(unsigned long long*)(sq + 256 + lane * 4) = 0ULL;
#pragma unroll
      for (int r = 0; r < 4; ++r)
        sq[(l15 >> 3) * 128 + (quad * 4 + r) * 8 + (l15 & 7)] = pb[r];

      short8 ap = *(const short8*)(sq + quad * 128 + l15 * 8);
#pragma unroll
      for (int dh = 0; dh < 2; ++dh) {
        short8 bv8 = *(const short8*)(sv8 + dh * 256 + (quad & 1) * 128 + l15 * 8);
        floatx4 oacc = MFMA16(ap, bv8, ((floatx4){0.f, 0.f, 0.f, 0.f}));
#pragma unroll
        for (int r = 0; r < 4; ++r) {
          const int t = tq + r;
          Of[(t * 32 + h * 4 + dh * 2 + (l15 >> 3)) * 64 + wwin * 8 + (l15 & 7)] =
              f2bf(oacc[r]);
        }
      }
    }
  }
  __syncthreads();

  {
    const int w8 = (l15 & 7) * 8;
    floatx4 pacc[4];
#pragma unroll
    for (int ni = 0; ni < 4; ++ni) pacc[ni] = (floatx4){0.f, 0.f, 0.f, 0.f};
#pragma unroll 4
    for (int kc = 0; kc < 64; ++kc) {
      short8 afr = *(const short8*)(Of + (kc * 4 + quad) * 64 + w8);
#pragma unroll
      for (int ni = 0; ni < 4; ++ni) {
        const int n = w * 64 + ni * 16 + l15;
        short8 bfr = *(const short8*)(sWf + ((kc * 4 + quad) * 256 + n) * 8);
        pacc[ni] = MFMA16(afr, bfr, pacc[ni]);
      }
    }
    if (quad < 2) {
      if (flag) {
        float* po = (float*)out;
#pragma unroll
        for (int ni = 0; ni < 4; ++ni) {
          const int n = w * 64 + ni * 16 + l15;
          const float bb = fbf[n];
#pragma unroll
          for (int r = 0; r < 4; ++r)
            po[(blockIdx.x * 8 + quad * 4 + r) * 256 + n] = pacc[ni][r] + bb;
        }
      } else {
        u16* po = (u16*)out;
#pragma unroll
        for (int ni = 0; ni < 4; ++ni) {
          const int n = w * 64 + ni * 16 + l15;
          const float bb = fbf[n];
#pragma unroll
          for (int r = 0; r < 4; ++r)
            po[(blockIdx.x * 8 + quad * 4 + r) * 256 + n] = f2bf(pacc[ni][r] + bb);
        }
      }
    }
  }
}

extern "C" void kernel_launch(void* const* d_in, const int* in_sizes, int n_in,
                              void* d_out, int out_size, void* d_ws, size_t ws_size,
                              hipStream_t stream) {
  (void)in_sizes; (void)n_in; (void)out_size;
  int* flag = (int*)d_ws;
  u16* ws = (u16*)d_ws;

  detect_kernel<<<1, 64, 0, stream>>>((const u16*)d_in[0], flag);
  prep_kernel<<<4136, 256, 0, stream>>>(flag,
      d_in[0], d_in[1], d_in[2], d_in[3], d_in[4], d_in[5], d_in[6], d_in[7],
      d_in[8], d_in[9], d_in[10], d_in[11], d_in[12], d_in[13], d_in[14], ws);
  fusew_kernel<<<32, 256, 0, stream>>>(ws + OF_WOC, ws + OF_WPS, ws + OF_WF);
  bfused_kernel<<<1, 256, 0, stream>>>(ws + OF_SMALL, ws + OF_WPS,
                                       (float*)(ws + OF_BF));

  if ((unsigned long long)ws_size >= WS_NEED) {
    // split path: high-occupancy attention kernel + pure patch GEMM
    attn_kernel<<<3200, 256, 0, stream>>>(
        ws + OF_SPEC, ws + OF_SMALL,
        ws + OF_W, ws + OF_W + 65536, ws + OF_W + 2 * 65536, ws + OF_W + 3 * 65536,
        ws + OF_AG);
    patch_kernel<<<800, 256, 0, stream>>>(
        ws + OF_AG, ws + OF_WF, (const float*)(ws + OF_BF), flag, d_out);
  } else {
    fused_kernel<<<3200, 256, 0, stream>>>(
        ws + OF_SPEC, ws + OF_SMALL,
        ws + OF_W, ws + OF_W + 65536, ws + OF_W + 2 * 65536, ws + OF_W + 3 * 65536,
        ws + OF_WF, (const float*)(ws + OF_BF),
        flag, d_out);
  }
}